// Round 6
// baseline (241.529 us; speedup 1.0000x reference)
//
#include <hip/hip_runtime.h>
#include <stdint.h>

// Shapes (fixed): x [4,2048,1024] f32, qkv_w [3072,1024] f32, out_w [1024,1024] f32,
// out_b [1024] f32, out [4,2048,1024] f32.
// Pipeline: cvt->bf16 (fused), GEMM qkv = x@qkv_w^T, flash attn (32x32 S^T/O^T,
// in-reg softmax, cross-tile PV pipeline, counted-vmcnt barriers, balanced-triple
// partition at 3 blocks/CU), GEMM out = attn@out_w^T + b.

typedef __bf16 bfx8 __attribute__((ext_vector_type(8)));
typedef float f32x4 __attribute__((ext_vector_type(4)));
typedef float f32x16 __attribute__((ext_vector_type(16)));

__device__ __forceinline__ uint16_t f2b(float f) {
  uint32_t u = __float_as_uint(f);
  u += 0x7fff + ((u >> 16) & 1);   // RNE
  return (uint16_t)(u >> 16);
}

__device__ __forceinline__ uint32_t cvt_pk(float lo, float hi) {
  uint32_t r;
  asm("v_cvt_pk_bf16_f32 %0, %1, %2" : "=v"(r) : "v"(lo), "v"(hi));
  return r;
}

__device__ __forceinline__ void gld16(const void* g, void* l) {
  __builtin_amdgcn_global_load_lds((const __attribute__((address_space(1))) void*)g,
                                   (__attribute__((address_space(3))) void*)l,
                                   16, 0, 0);
}

// ---------------- fused f32 -> bf16 convert (8 elems/thread, 3 tensors) -----------
__global__ __launch_bounds__(256) void cvt_all(const float* __restrict__ x,
                                               const float* __restrict__ w1,
                                               const float* __restrict__ w2,
                                               uint16_t* __restrict__ xb,
                                               uint16_t* __restrict__ w1b,
                                               uint16_t* __restrict__ w2b) {
  int i = blockIdx.x * 256 + threadIdx.x;
  const float* in;
  uint16_t* out;
  if (i < 1048576) { in = x; out = xb; }
  else if (i < 1048576 + 393216) { in = w1; out = w1b; i -= 1048576; }
  else { in = w2; out = w2b; i -= 1048576 + 393216; }
  float4 a = ((const float4*)in)[2 * i];
  float4 b = ((const float4*)in)[2 * i + 1];
  union { uint16_t u[8]; uint4 v; } pk;
  pk.u[0] = f2b(a.x); pk.u[1] = f2b(a.y); pk.u[2] = f2b(a.z); pk.u[3] = f2b(a.w);
  pk.u[4] = f2b(b.x); pk.u[5] = f2b(b.y); pk.u[6] = f2b(b.z); pk.u[7] = f2b(b.w);
  ((uint4*)out)[i] = pk.v;
}

// ---------------- GEMM: C[M,N] = A[M,K] * B[N,K]^T (+bias) ----------------
template <int OUTF32>
__global__ __launch_bounds__(256) void gemm_bt(const uint16_t* __restrict__ A,
                                               const uint16_t* __restrict__ B,
                                               void* __restrict__ Cout,
                                               const float* __restrict__ bias,
                                               int M, int N, int K, int nbx, int nwg) {
  __shared__ alignas(16) uint16_t As[2][128 * 32];
  __shared__ alignas(16) uint16_t Bs[2][128 * 32];

  int did = blockIdx.x;
  int wg = (did & 7) * (nwg >> 3) + (did >> 3);
  int bx = wg % nbx, by = wg / nbx;
  int m0 = by * 128, n0 = bx * 128;

  int tid = threadIdx.x;
  int lane = tid & 63, wid = tid >> 6;
  int wm = wid >> 1, wn = wid & 1;

  int rs = wid * 16 + (lane >> 2);
  int cs = (lane & 3) * 8;

  f32x4 acc[4][4] = {};

  auto stage = [&](int buf, int kt) {
    int k0 = kt * 32;
    gld16(&A[(size_t)(m0 + rs) * K + k0 + cs],      &As[buf][wid * 512]);
    gld16(&A[(size_t)(m0 + rs + 64) * K + k0 + cs], &As[buf][wid * 512 + 2048]);
    gld16(&B[(size_t)(n0 + rs) * K + k0 + cs],      &Bs[buf][wid * 512]);
    gld16(&B[(size_t)(n0 + rs + 64) * K + k0 + cs], &Bs[buf][wid * 512 + 2048]);
  };

  stage(0, 0);
  __syncthreads();

  int nk = K >> 5;
  int cur = 0;
  int ko = (lane >> 4) * 8;
  for (int kt = 0; kt < nk; ++kt) {
    if (kt + 1 < nk) stage(cur ^ 1, kt + 1);
    bfx8 a[4], b[4];
#pragma unroll
    for (int mi = 0; mi < 4; ++mi)
      a[mi] = *(const bfx8*)&As[cur][(wm * 64 + mi * 16 + (lane & 15)) * 32 + ko];
#pragma unroll
    for (int ni = 0; ni < 4; ++ni)
      b[ni] = *(const bfx8*)&Bs[cur][(wn * 64 + ni * 16 + (lane & 15)) * 32 + ko];
#pragma unroll
    for (int mi = 0; mi < 4; ++mi)
#pragma unroll
      for (int ni = 0; ni < 4; ++ni)
        acc[mi][ni] =
            __builtin_amdgcn_mfma_f32_16x16x32_bf16(a[mi], b[ni], acc[mi][ni], 0, 0, 0);
    __syncthreads();
    cur ^= 1;
  }

#pragma unroll
  for (int mi = 0; mi < 4; ++mi) {
    int row = m0 + wm * 64 + mi * 16 + ((lane >> 4) << 2);
#pragma unroll
    for (int ni = 0; ni < 4; ++ni) {
      int col = n0 + wn * 64 + ni * 16 + (lane & 15);
#pragma unroll
      for (int r = 0; r < 4; ++r) {
        float v = acc[mi][ni][r];
        if (OUTF32)
          ((float*)Cout)[(size_t)(row + r) * N + col] = v + bias[col];
        else
          ((uint16_t*)Cout)[(size_t)(row + r) * N + col] = f2b(v);
      }
    }
  }
}

// ---------------- flash attention (causal), pipelined 32x32 S^T / O^T ----------
// 768 blocks = 3/CU. Per (b,h): qb tiles t(qb)=2qb+2 (sum 272) split into 4 triples
// of EXACTLY 68 tiles: (15-tr | 8+tr | pair{7-tr, tr}), tr=0..3. Blocks c, c+256,
// c+512 form one triple (round-robin dispatch -> same CU): per-CU load uniform.
// 4 waves x 32 q. Distance-2 prefetch; K triple-buffered LDS (global_load_lds),
// V triple-buffered LDS via 2-bank register staging. Raw s_barrier with COUNTED
// vmcnt(4). Buffer rotation mod 3 disjoint. Per-wave code identical to round 5.
__global__ __launch_bounds__(256, 3) void flash_attn(const uint16_t* __restrict__ qkv,
                                                     uint16_t* __restrict__ attnb) {
  const int T = 2048, D3 = 3072;
  const float CSC = 0.125f * 1.44269504f;  // scale * log2(e)
  __shared__ alignas(16) uint16_t Ks[3][64 * 64];
  __shared__ alignas(16) uint16_t Vt[3][64 * 64];   // V^T: [hd][kv]

  int did = blockIdx.x;
  int c = did & 255;             // CU coset
  int j = did >> 8;              // 0,1,2: member of the triple
  int bh = c >> 2, tr = c & 3;
  int b = bh >> 4, h = bh & 15;

  int tid = threadIdx.x, lane = tid & 63, wid = tid >> 6;
  int l31 = lane & 31, hi = lane >> 5;
  int swz = (lane & 7) << 3;

  size_t base = (size_t)b * T * D3;
  int hoff = h * 64;
  const uint16_t* kbase = &qkv[base + 1024 + hoff];
  const uint16_t* vbase = &qkv[base + 2048 + hoff];

  int krow = wid * 16 + (lane >> 3);
  int kc = ((lane & 7) << 3) ^ ((krow & 7) << 3);
  int vr = (tid & 31) * 2;
  int vc = (tid >> 5) * 8;

  int nparts = (j == 2) ? 2 : 1;
  for (int p = 0; p < nparts; ++p) {
    int qb = (j == 0) ? (15 - tr) : (j == 1) ? (8 + tr) : ((p == 0) ? (7 - tr) : tr);
    int q0 = qb << 7;
    int qw = q0 + wid * 32;
    int ntile = 2 * qb + 2;             // even

    float mC = -1e30f, l_r = 0.f;       // l_r: per-lane partial
    f32x16 acc0 = {}, acc1 = {};
    bfx8 pf[4];
    int smax_prev = -1, vb_prev = 0;

    // Q frags (B-operand): col=q=l31, k = hd = 16*h4 + 8*hi + j
    bfx8 qf[4];
    {
      const uint16_t* qp = &qkv[base + (size_t)(qw + l31) * D3 + hoff + 8 * hi];
#pragma unroll
      for (int h4 = 0; h4 < 4; ++h4) qf[h4] = *(const bfx8*)(qp + 16 * h4);
    }

    uint4 vA0, vA1, vB0, vB1;   // two V register banks (tile parity)

    auto loadV = [&](int kv0, uint4& r0, uint4& r1) {
      r0 = *(const uint4*)&vbase[(size_t)(kv0 + vr) * D3 + vc];
      r1 = *(const uint4*)&vbase[(size_t)(kv0 + vr + 1) * D3 + vc];
    };
    auto stageK = [&](int buf, int kv0) {
      gld16(&kbase[(size_t)(kv0 + krow) * D3 + kc], &Ks[buf][wid * 1024]);
      gld16(&kbase[(size_t)(kv0 + krow + 8) * D3 + kc], &Ks[buf][wid * 1024 + 512]);
    };
    auto writeV = [&](int vb, const uint4& r0, const uint4& r1) {
      union { uint4 v; uint16_t u[8]; } x, y;
      x.v = r0; y.v = r1;
#pragma unroll
      for (int jj = 0; jj < 8; ++jj) {
        int hd = vc + jj;
        uint32_t pk = (uint32_t)x.u[jj] | ((uint32_t)y.u[jj] << 16);
        *(uint32_t*)&Vt[vb][hd * 64 + (vr ^ ((hd & 7) << 3))] = pk;
      }
    };
    auto doPV = [&]() {
      const uint16_t* vp = &Vt[vb_prev][0];
      __builtin_amdgcn_s_setprio(1);
#pragma unroll
      for (int s = 0; s < 4; ++s) {
        if (s <= smax_prev) {
          bfx8 v0 = *(const bfx8*)&vp[l31 * 64 + ((16 * s + 8 * hi) ^ swz)];
          acc0 = __builtin_amdgcn_mfma_f32_32x32x16_bf16(v0, pf[s], acc0, 0, 0, 0);
          bfx8 v1 = *(const bfx8*)&vp[(32 + l31) * 64 + ((16 * s + 8 * hi) ^ swz)];
          acc1 = __builtin_amdgcn_mfma_f32_32x32x16_bf16(v1, pf[s], acc1, 0, 0, 0);
        }
      }
      __builtin_amdgcn_s_setprio(0);
    };

    // ---- prologue: stage tiles 0,1 fully; full drain once ----
    loadV(0, vA0, vA1);
    stageK(0, 0);
    writeV(0, vA0, vA1);          // compiler inserts the vmcnt wait for vA regs
    loadV(64, vB0, vB1);          // tile 1 -> bank B (written at iter 0)
    stageK(1, 64);
    asm volatile("s_waitcnt vmcnt(0) lgkmcnt(0)" ::: "memory");
    __builtin_amdgcn_s_barrier();
    __builtin_amdgcn_sched_barrier(0);

    auto subiter = [&](int t, uint4& f0, uint4& f1, uint4& c0, uint4& c1) {
      int kv0 = t << 6;
      bool issue = (t + 2 < ntile);
      if (issue) {
        loadV((t + 2) << 6, f0, f1);
        stageK((t + 2) % 3, (t + 2) << 6);
      }
      bool active = (kv0 <= qw);
      int tmax = (qw > kv0) ? 2 : 1;
      f32x16 st0 = {}, st1 = {};
      if (active) {
        // ---- S^T = K * Q^T ----
        const uint16_t* kp = &Ks[t % 3][0];
        __builtin_amdgcn_s_setprio(1);
#pragma unroll
        for (int h4 = 0; h4 < 4; ++h4) {
          bfx8 kf0 = *(const bfx8*)&kp[l31 * 64 + ((16 * h4 + 8 * hi) ^ swz)];
          st0 = __builtin_amdgcn_mfma_f32_32x32x16_bf16(kf0, qf[h4], st0, 0, 0, 0);
          if (tmax == 2) {
            bfx8 kf1 = *(const bfx8*)&kp[(32 + l31) * 64 + ((16 * h4 + 8 * hi) ^ swz)];
            st1 = __builtin_amdgcn_mfma_f32_32x32x16_bf16(kf1, qf[h4], st1, 0, 0, 0);
          }
        }
        __builtin_amdgcn_s_setprio(0);
      }

      // ---- PV of PREVIOUS tile (before any rescale of acc) ----
      if (smax_prev >= 0) { doPV(); smax_prev = -1; }

      if (active) {
        // ---- softmax (lane-local rows; st becomes P in place) ----
        int q = qw + l31;
        float mx0 = -1e30f, mx1 = -1e30f;
        if (kv0 == qw) {
#pragma unroll
          for (int r = 0; r < 16; ++r) {
            int kv = kv0 + (r & 3) + 8 * (r >> 2) + 4 * hi;
            float v = st0[r];
            if (kv > q) v = -1e30f;
            st0[r] = v;
            mx0 = fmaxf(mx0, v);
          }
        } else {
#pragma unroll
          for (int r = 0; r < 16; ++r) mx0 = fmaxf(mx0, st0[r]);
        }
        if (tmax == 2) {
          if (kv0 + 32 == qw) {
#pragma unroll
            for (int r = 0; r < 16; ++r) {
              int kv = kv0 + 32 + (r & 3) + 8 * (r >> 2) + 4 * hi;
              float v = st1[r];
              if (kv > q) v = -1e30f;
              st1[r] = v;
              mx1 = fmaxf(mx1, v);
            }
          } else {
#pragma unroll
            for (int r = 0; r < 16; ++r) mx1 = fmaxf(mx1, st1[r]);
          }
        }
        float mS = fmaxf(mx0, mx1) * CSC;
        if (!__all(mS - mC <= 8.0f)) {   // defer-max: rare path has the only shuffle
          float mSp = fmaxf(mS, __shfl_xor(mS, 32));
          float mCn = fmaxf(mC, mSp);
          float fac = __builtin_amdgcn_exp2f(mC - mCn);
          mC = mCn;
          l_r *= fac;
          acc0 *= fac;
          acc1 *= fac;
        }
        float l0 = 0.f, l1 = 0.f, l2 = 0.f, l3 = 0.f;
#pragma unroll
        for (int r = 0; r < 16; r += 4) {
          float e0 = __builtin_amdgcn_exp2f(fmaf(st0[r], CSC, -mC));
          float e1 = __builtin_amdgcn_exp2f(fmaf(st0[r + 1], CSC, -mC));
          float e2 = __builtin_amdgcn_exp2f(fmaf(st0[r + 2], CSC, -mC));
          float e3 = __builtin_amdgcn_exp2f(fmaf(st0[r + 3], CSC, -mC));
          st0[r] = e0; st0[r + 1] = e1; st0[r + 2] = e2; st0[r + 3] = e3;
          l0 += e0; l1 += e1; l2 += e2; l3 += e3;
        }
        if (tmax == 2) {
#pragma unroll
          for (int r = 0; r < 16; r += 4) {
            float e0 = __builtin_amdgcn_exp2f(fmaf(st1[r], CSC, -mC));
            float e1 = __builtin_amdgcn_exp2f(fmaf(st1[r + 1], CSC, -mC));
            float e2 = __builtin_amdgcn_exp2f(fmaf(st1[r + 2], CSC, -mC));
            float e3 = __builtin_amdgcn_exp2f(fmaf(st1[r + 3], CSC, -mC));
            st1[r] = e0; st1[r + 1] = e1; st1[r + 2] = e2; st1[r + 3] = e3;
            l0 += e0; l1 += e1; l2 += e2; l3 += e3;
          }
        }
        l_r += (l0 + l1) + (l2 + l3);

        // ---- pack P -> bf16 B-frags in registers ----
        int smax = (qw + 31 - kv0) >> 4;
        if (smax > 3) smax = 3;
#pragma unroll
        for (int s = 0; s < 4; ++s) {
          if (s <= smax) {
            int pb = 8 * (s & 1);
            uint32_t W0, W1, W2, W3;
            if (s < 2) {
              W0 = cvt_pk(st0[pb + 0], st0[pb + 1]);
              W1 = cvt_pk(st0[pb + 2], st0[pb + 3]);
              W2 = cvt_pk(st0[pb + 4], st0[pb + 5]);
              W3 = cvt_pk(st0[pb + 6], st0[pb + 7]);
            } else {
              W0 = cvt_pk(st1[pb + 0], st1[pb + 1]);
              W1 = cvt_pk(st1[pb + 2], st1[pb + 3]);
              W2 = cvt_pk(st1[pb + 4], st1[pb + 5]);
              W3 = cvt_pk(st1[pb + 6], st1[pb + 7]);
            }
            auto rA = __builtin_amdgcn_permlane32_swap(W0, W2, false, false);
            auto rB = __builtin_amdgcn_permlane32_swap(W1, W3, false, false);
            union { uint32_t u[4]; bfx8 v; } pk;
            pk.u[0] = rA[0]; pk.u[1] = rB[0]; pk.u[2] = rA[1]; pk.u[3] = rB[1];
            pf[s] = pk.v;
          }
        }
        smax_prev = smax;
        vb_prev = t % 3;
      }

      if (t + 1 < ntile) writeV((t + 1) % 3, c0, c1);

      if (issue)
        asm volatile("s_waitcnt vmcnt(4) lgkmcnt(0)" ::: "memory");  // keep this iter's 4 in flight
      else
        asm volatile("s_waitcnt vmcnt(0) lgkmcnt(0)" ::: "memory");  // tail: full drain
      __builtin_amdgcn_s_barrier();
      __builtin_amdgcn_sched_barrier(0);
    };

    for (int t = 0; t < ntile; t += 2) {
      subiter(t, vA0, vA1, vB0, vB1);       // fill A (tile t+2), consume B (tile t+1)
      subiter(t + 1, vB0, vB1, vA0, vA1);   // fill B (tile t+3), consume A (tile t+2)
    }
    if (smax_prev >= 0) doPV();

    // ---- epilogue: merge l across lane pair, normalize, transpose, store ----
    float l_tot = l_r + __shfl_xor(l_r, 32);
    __syncthreads();   // all waves done reading K/V LDS before overlay
    uint16_t* ow = ((uint16_t*)Ks) + wid * 2048;  // per-warp [32 q][64 hd] (warp-private)
    float rl = 1.0f / l_tot;
#pragma unroll
    for (int f = 0; f < 2; ++f) {
#pragma unroll
      for (int r = 0; r < 16; r += 2) {
        int hd = 32 * f + (r & 3) + 8 * (r >> 2) + 4 * hi;
        float v0 = (f ? acc1[r] : acc0[r]) * rl;
        float v1 = (f ? acc1[r + 1] : acc0[r + 1]) * rl;
        *(uint32_t*)&ow[l31 * 64 + (hd ^ ((l31 & 7) << 3))] = cvt_pk(v0, v1);
      }
    }
    // warp-private region: no barrier needed between write and read
    int row = lane >> 1, cb = (lane & 1) * 32;
    int q = q0 + wid * 32 + row;
    int rs = (row & 7) << 3;
    uint16_t* dst = &attnb[(size_t)(b * T + q) * 1024 + hoff + cb];
#pragma unroll
    for (int cc = 0; cc < 4; ++cc)
      *(uint4*)&dst[cc * 8] = *(const uint4*)&ow[row * 64 + ((cb + cc * 8) ^ rs)];
    __syncthreads();   // epilogue reads done before next part restages Ks
  }
}

// ---------------- host ----------------
extern "C" void kernel_launch(void* const* d_in, const int* in_sizes, int n_in,
                              void* d_out, int out_size, void* d_ws, size_t ws_size,
                              hipStream_t stream) {
  const float* x = (const float*)d_in[0];
  const float* qkv_w = (const float*)d_in[1];
  const float* out_w = (const float*)d_in[2];
  const float* out_b = (const float*)d_in[3];
  float* out = (float*)d_out;

  char* ws = (char*)d_ws;
  uint16_t* xb    = (uint16_t*)(ws);
  uint16_t* qkvb  = (uint16_t*)(ws + 16777216);
  uint16_t* attnb = (uint16_t*)(ws + 67108864);
  uint16_t* wqkvb = (uint16_t*)(ws + 83886080);
  uint16_t* wob   = (uint16_t*)(ws + 90177536);

  cvt_all<<<6144, 256, 0, stream>>>(x, qkv_w, out_w, xb, wqkvb, wob);

  gemm_bt<0><<<1536, 256, 0, stream>>>(xb, wqkvb, (void*)qkvb, nullptr,
                                       8192, 3072, 1024, 24, 1536);
  flash_attn<<<768, 256, 0, stream>>>(qkvb, attnb);
  gemm_bt<1><<<512, 256, 0, stream>>>(attnb, wob, (void*)out, out_b,
                                      8192, 1024, 1024, 8, 512);
}

// Round 7
// 205.614 us; speedup vs baseline: 1.1747x; 1.1747x over previous
//
#include <hip/hip_runtime.h>
#include <stdint.h>

// Shapes (fixed): x [4,2048,1024] f32, qkv_w [3072,1024] f32, out_w [1024,1024] f32,
// out_b [1024] f32, out [4,2048,1024] f32.
// Pipeline: cvt->bf16 (fused), GEMM qkv = x@qkv_w^T, flash attn (32x32 S^T/O^T,
// in-reg softmax, cross-tile PV pipeline, counted-vmcnt barriers, balanced-triple
// partition, 3 blocks/CU via LDS limit -- NOT via launch_bounds; (256,3) caused a
// VGPR spill storm in round 6: VGPR 124->84, scratch traffic 73MB writes),
// GEMM out = attn@out_w^T + b.

typedef __bf16 bfx8 __attribute__((ext_vector_type(8)));
typedef float f32x4 __attribute__((ext_vector_type(4)));
typedef float f32x16 __attribute__((ext_vector_type(16)));

__device__ __forceinline__ uint16_t f2b(float f) {
  uint32_t u = __float_as_uint(f);
  u += 0x7fff + ((u >> 16) & 1);   // RNE
  return (uint16_t)(u >> 16);
}

__device__ __forceinline__ uint32_t cvt_pk(float lo, float hi) {
  uint32_t r;
  asm("v_cvt_pk_bf16_f32 %0, %1, %2" : "=v"(r) : "v"(lo), "v"(hi));
  return r;
}

__device__ __forceinline__ void gld16(const void* g, void* l) {
  __builtin_amdgcn_global_load_lds((const __attribute__((address_space(1))) void*)g,
                                   (__attribute__((address_space(3))) void*)l,
                                   16, 0, 0);
}

// ---------------- fused f32 -> bf16 convert (8 elems/thread, 3 tensors) -----------
__global__ __launch_bounds__(256) void cvt_all(const float* __restrict__ x,
                                               const float* __restrict__ w1,
                                               const float* __restrict__ w2,
                                               uint16_t* __restrict__ xb,
                                               uint16_t* __restrict__ w1b,
                                               uint16_t* __restrict__ w2b) {
  int i = blockIdx.x * 256 + threadIdx.x;
  const float* in;
  uint16_t* out;
  if (i < 1048576) { in = x; out = xb; }
  else if (i < 1048576 + 393216) { in = w1; out = w1b; i -= 1048576; }
  else { in = w2; out = w2b; i -= 1048576 + 393216; }
  float4 a = ((const float4*)in)[2 * i];
  float4 b = ((const float4*)in)[2 * i + 1];
  union { uint16_t u[8]; uint4 v; } pk;
  pk.u[0] = f2b(a.x); pk.u[1] = f2b(a.y); pk.u[2] = f2b(a.z); pk.u[3] = f2b(a.w);
  pk.u[4] = f2b(b.x); pk.u[5] = f2b(b.y); pk.u[6] = f2b(b.z); pk.u[7] = f2b(b.w);
  ((uint4*)out)[i] = pk.v;
}

// ---------------- GEMM: C[M,N] = A[M,K] * B[N,K]^T (+bias) ----------------
template <int OUTF32>
__global__ __launch_bounds__(256) void gemm_bt(const uint16_t* __restrict__ A,
                                               const uint16_t* __restrict__ B,
                                               void* __restrict__ Cout,
                                               const float* __restrict__ bias,
                                               int M, int N, int K, int nbx, int nwg) {
  __shared__ alignas(16) uint16_t As[2][128 * 32];
  __shared__ alignas(16) uint16_t Bs[2][128 * 32];

  int did = blockIdx.x;
  int wg = (did & 7) * (nwg >> 3) + (did >> 3);
  int bx = wg % nbx, by = wg / nbx;
  int m0 = by * 128, n0 = bx * 128;

  int tid = threadIdx.x;
  int lane = tid & 63, wid = tid >> 6;
  int wm = wid >> 1, wn = wid & 1;

  int rs = wid * 16 + (lane >> 2);
  int cs = (lane & 3) * 8;

  f32x4 acc[4][4] = {};

  auto stage = [&](int buf, int kt) {
    int k0 = kt * 32;
    gld16(&A[(size_t)(m0 + rs) * K + k0 + cs],      &As[buf][wid * 512]);
    gld16(&A[(size_t)(m0 + rs + 64) * K + k0 + cs], &As[buf][wid * 512 + 2048]);
    gld16(&B[(size_t)(n0 + rs) * K + k0 + cs],      &Bs[buf][wid * 512]);
    gld16(&B[(size_t)(n0 + rs + 64) * K + k0 + cs], &Bs[buf][wid * 512 + 2048]);
  };

  stage(0, 0);
  __syncthreads();

  int nk = K >> 5;
  int cur = 0;
  int ko = (lane >> 4) * 8;
  for (int kt = 0; kt < nk; ++kt) {
    if (kt + 1 < nk) stage(cur ^ 1, kt + 1);
    bfx8 a[4], b[4];
#pragma unroll
    for (int mi = 0; mi < 4; ++mi)
      a[mi] = *(const bfx8*)&As[cur][(wm * 64 + mi * 16 + (lane & 15)) * 32 + ko];
#pragma unroll
    for (int ni = 0; ni < 4; ++ni)
      b[ni] = *(const bfx8*)&Bs[cur][(wn * 64 + ni * 16 + (lane & 15)) * 32 + ko];
#pragma unroll
    for (int mi = 0; mi < 4; ++mi)
#pragma unroll
      for (int ni = 0; ni < 4; ++ni)
        acc[mi][ni] =
            __builtin_amdgcn_mfma_f32_16x16x32_bf16(a[mi], b[ni], acc[mi][ni], 0, 0, 0);
    __syncthreads();
    cur ^= 1;
  }

#pragma unroll
  for (int mi = 0; mi < 4; ++mi) {
    int row = m0 + wm * 64 + mi * 16 + ((lane >> 4) << 2);
#pragma unroll
    for (int ni = 0; ni < 4; ++ni) {
      int col = n0 + wn * 64 + ni * 16 + (lane & 15);
#pragma unroll
      for (int r = 0; r < 4; ++r) {
        float v = acc[mi][ni][r];
        if (OUTF32)
          ((float*)Cout)[(size_t)(row + r) * N + col] = v + bias[col];
        else
          ((uint16_t*)Cout)[(size_t)(row + r) * N + col] = f2b(v);
      }
    }
  }
}

// ---------------- flash attention (causal), pipelined 32x32 S^T / O^T ----------
// 768 blocks. Per (b,h): qb tiles t(qb)=2qb+2 (sum 272) split into 4 triples of
// EXACTLY 68 tiles: (15-tr | 8+tr | pair{7-tr, tr}), tr=0..3. Blocks c, c+256,
// c+512 form one triple (round-robin dispatch -> same CU): per-CU load uniform.
// Residency: LDS 48KB -> 3 blocks/CU. launch_bounds kept at (256,2): (256,3)
// forced VGPR 124->84 and spilled (round-6 regression: 73MB scratch writes).
// 4 waves x 32 q. Distance-2 prefetch; K triple-buffered LDS (global_load_lds),
// V triple-buffered LDS via 2-bank register staging. Raw s_barrier with COUNTED
// vmcnt(4). Buffer rotation mod 3 disjoint.
__global__ __launch_bounds__(256, 2) void flash_attn(const uint16_t* __restrict__ qkv,
                                                     uint16_t* __restrict__ attnb) {
  const int T = 2048, D3 = 3072;
  const float CSC = 0.125f * 1.44269504f;  // scale * log2(e)
  __shared__ alignas(16) uint16_t Ks[3][64 * 64];
  __shared__ alignas(16) uint16_t Vt[3][64 * 64];   // V^T: [hd][kv]

  int did = blockIdx.x;
  int c = did & 255;             // CU coset
  int j = did >> 8;              // 0,1,2: member of the triple
  int bh = c >> 2, tr = c & 3;
  int b = bh >> 4, h = bh & 15;

  int tid = threadIdx.x, lane = tid & 63, wid = tid >> 6;
  int l31 = lane & 31, hi = lane >> 5;
  int swz = (lane & 7) << 3;

  size_t base = (size_t)b * T * D3;
  int hoff = h * 64;
  const uint16_t* kbase = &qkv[base + 1024 + hoff];
  const uint16_t* vbase = &qkv[base + 2048 + hoff];

  int krow = wid * 16 + (lane >> 3);
  int kc = ((lane & 7) << 3) ^ ((krow & 7) << 3);
  int vr = (tid & 31) * 2;
  int vc = (tid >> 5) * 8;

  int nparts = (j == 2) ? 2 : 1;
  for (int p = 0; p < nparts; ++p) {
    int qb = (j == 0) ? (15 - tr) : (j == 1) ? (8 + tr) : ((p == 0) ? (7 - tr) : tr);
    int q0 = qb << 7;
    int qw = q0 + wid * 32;
    int ntile = 2 * qb + 2;             // even

    float mC = -1e30f, l_r = 0.f;       // l_r: per-lane partial
    f32x16 acc0 = {}, acc1 = {};
    bfx8 pf[4];
    int smax_prev = -1, vb_prev = 0;

    // Q frags (B-operand): col=q=l31, k = hd = 16*h4 + 8*hi + j
    bfx8 qf[4];
    {
      const uint16_t* qp = &qkv[base + (size_t)(qw + l31) * D3 + hoff + 8 * hi];
#pragma unroll
      for (int h4 = 0; h4 < 4; ++h4) qf[h4] = *(const bfx8*)(qp + 16 * h4);
    }

    uint4 vA0, vA1, vB0, vB1;   // two V register banks (tile parity)

    auto loadV = [&](int kv0, uint4& r0, uint4& r1) {
      r0 = *(const uint4*)&vbase[(size_t)(kv0 + vr) * D3 + vc];
      r1 = *(const uint4*)&vbase[(size_t)(kv0 + vr + 1) * D3 + vc];
    };
    auto stageK = [&](int buf, int kv0) {
      gld16(&kbase[(size_t)(kv0 + krow) * D3 + kc], &Ks[buf][wid * 1024]);
      gld16(&kbase[(size_t)(kv0 + krow + 8) * D3 + kc], &Ks[buf][wid * 1024 + 512]);
    };
    auto writeV = [&](int vb, const uint4& r0, const uint4& r1) {
      union { uint4 v; uint16_t u[8]; } x, y;
      x.v = r0; y.v = r1;
#pragma unroll
      for (int jj = 0; jj < 8; ++jj) {
        int hd = vc + jj;
        uint32_t pk = (uint32_t)x.u[jj] | ((uint32_t)y.u[jj] << 16);
        *(uint32_t*)&Vt[vb][hd * 64 + (vr ^ ((hd & 7) << 3))] = pk;
      }
    };
    auto doPV = [&]() {
      const uint16_t* vp = &Vt[vb_prev][0];
      __builtin_amdgcn_s_setprio(1);
#pragma unroll
      for (int s = 0; s < 4; ++s) {
        if (s <= smax_prev) {
          bfx8 v0 = *(const bfx8*)&vp[l31 * 64 + ((16 * s + 8 * hi) ^ swz)];
          acc0 = __builtin_amdgcn_mfma_f32_32x32x16_bf16(v0, pf[s], acc0, 0, 0, 0);
          bfx8 v1 = *(const bfx8*)&vp[(32 + l31) * 64 + ((16 * s + 8 * hi) ^ swz)];
          acc1 = __builtin_amdgcn_mfma_f32_32x32x16_bf16(v1, pf[s], acc1, 0, 0, 0);
        }
      }
      __builtin_amdgcn_s_setprio(0);
    };

    // ---- prologue: stage tiles 0,1 fully; full drain once ----
    loadV(0, vA0, vA1);
    stageK(0, 0);
    writeV(0, vA0, vA1);          // compiler inserts the vmcnt wait for vA regs
    loadV(64, vB0, vB1);          // tile 1 -> bank B (written at iter 0)
    stageK(1, 64);
    asm volatile("s_waitcnt vmcnt(0) lgkmcnt(0)" ::: "memory");
    __builtin_amdgcn_s_barrier();
    __builtin_amdgcn_sched_barrier(0);

    auto subiter = [&](int t, uint4& f0, uint4& f1, uint4& c0, uint4& c1) {
      int kv0 = t << 6;
      bool issue = (t + 2 < ntile);
      if (issue) {
        loadV((t + 2) << 6, f0, f1);
        stageK((t + 2) % 3, (t + 2) << 6);
      }
      bool active = (kv0 <= qw);
      int tmax = (qw > kv0) ? 2 : 1;
      f32x16 st0 = {}, st1 = {};
      if (active) {
        // ---- S^T = K * Q^T ----
        const uint16_t* kp = &Ks[t % 3][0];
        __builtin_amdgcn_s_setprio(1);
#pragma unroll
        for (int h4 = 0; h4 < 4; ++h4) {
          bfx8 kf0 = *(const bfx8*)&kp[l31 * 64 + ((16 * h4 + 8 * hi) ^ swz)];
          st0 = __builtin_amdgcn_mfma_f32_32x32x16_bf16(kf0, qf[h4], st0, 0, 0, 0);
          if (tmax == 2) {
            bfx8 kf1 = *(const bfx8*)&kp[(32 + l31) * 64 + ((16 * h4 + 8 * hi) ^ swz)];
            st1 = __builtin_amdgcn_mfma_f32_32x32x16_bf16(kf1, qf[h4], st1, 0, 0, 0);
          }
        }
        __builtin_amdgcn_s_setprio(0);
      }

      // ---- PV of PREVIOUS tile (before any rescale of acc) ----
      if (smax_prev >= 0) { doPV(); smax_prev = -1; }

      if (active) {
        // ---- softmax (lane-local rows; st becomes P in place) ----
        int q = qw + l31;
        float mx0 = -1e30f, mx1 = -1e30f;
        if (kv0 == qw) {
#pragma unroll
          for (int r = 0; r < 16; ++r) {
            int kv = kv0 + (r & 3) + 8 * (r >> 2) + 4 * hi;
            float v = st0[r];
            if (kv > q) v = -1e30f;
            st0[r] = v;
            mx0 = fmaxf(mx0, v);
          }
        } else {
#pragma unroll
          for (int r = 0; r < 16; ++r) mx0 = fmaxf(mx0, st0[r]);
        }
        if (tmax == 2) {
          if (kv0 + 32 == qw) {
#pragma unroll
            for (int r = 0; r < 16; ++r) {
              int kv = kv0 + 32 + (r & 3) + 8 * (r >> 2) + 4 * hi;
              float v = st1[r];
              if (kv > q) v = -1e30f;
              st1[r] = v;
              mx1 = fmaxf(mx1, v);
            }
          } else {
#pragma unroll
            for (int r = 0; r < 16; ++r) mx1 = fmaxf(mx1, st1[r]);
          }
        }
        float mS = fmaxf(mx0, mx1) * CSC;
        if (!__all(mS - mC <= 8.0f)) {   // defer-max: rare path has the only shuffle
          float mSp = fmaxf(mS, __shfl_xor(mS, 32));
          float mCn = fmaxf(mC, mSp);
          float fac = __builtin_amdgcn_exp2f(mC - mCn);
          mC = mCn;
          l_r *= fac;
          acc0 *= fac;
          acc1 *= fac;
        }
        float l0 = 0.f, l1 = 0.f, l2 = 0.f, l3 = 0.f;
#pragma unroll
        for (int r = 0; r < 16; r += 4) {
          float e0 = __builtin_amdgcn_exp2f(fmaf(st0[r], CSC, -mC));
          float e1 = __builtin_amdgcn_exp2f(fmaf(st0[r + 1], CSC, -mC));
          float e2 = __builtin_amdgcn_exp2f(fmaf(st0[r + 2], CSC, -mC));
          float e3 = __builtin_amdgcn_exp2f(fmaf(st0[r + 3], CSC, -mC));
          st0[r] = e0; st0[r + 1] = e1; st0[r + 2] = e2; st0[r + 3] = e3;
          l0 += e0; l1 += e1; l2 += e2; l3 += e3;
        }
        if (tmax == 2) {
#pragma unroll
          for (int r = 0; r < 16; r += 4) {
            float e0 = __builtin_amdgcn_exp2f(fmaf(st1[r], CSC, -mC));
            float e1 = __builtin_amdgcn_exp2f(fmaf(st1[r + 1], CSC, -mC));
            float e2 = __builtin_amdgcn_exp2f(fmaf(st1[r + 2], CSC, -mC));
            float e3 = __builtin_amdgcn_exp2f(fmaf(st1[r + 3], CSC, -mC));
            st1[r] = e0; st1[r + 1] = e1; st1[r + 2] = e2; st1[r + 3] = e3;
            l0 += e0; l1 += e1; l2 += e2; l3 += e3;
          }
        }
        l_r += (l0 + l1) + (l2 + l3);

        // ---- pack P -> bf16 B-frags in registers ----
        int smax = (qw + 31 - kv0) >> 4;
        if (smax > 3) smax = 3;
#pragma unroll
        for (int s = 0; s < 4; ++s) {
          if (s <= smax) {
            int pb = 8 * (s & 1);
            uint32_t W0, W1, W2, W3;
            if (s < 2) {
              W0 = cvt_pk(st0[pb + 0], st0[pb + 1]);
              W1 = cvt_pk(st0[pb + 2], st0[pb + 3]);
              W2 = cvt_pk(st0[pb + 4], st0[pb + 5]);
              W3 = cvt_pk(st0[pb + 6], st0[pb + 7]);
            } else {
              W0 = cvt_pk(st1[pb + 0], st1[pb + 1]);
              W1 = cvt_pk(st1[pb + 2], st1[pb + 3]);
              W2 = cvt_pk(st1[pb + 4], st1[pb + 5]);
              W3 = cvt_pk(st1[pb + 6], st1[pb + 7]);
            }
            auto rA = __builtin_amdgcn_permlane32_swap(W0, W2, false, false);
            auto rB = __builtin_amdgcn_permlane32_swap(W1, W3, false, false);
            union { uint32_t u[4]; bfx8 v; } pk;
            pk.u[0] = rA[0]; pk.u[1] = rB[0]; pk.u[2] = rA[1]; pk.u[3] = rB[1];
            pf[s] = pk.v;
          }
        }
        smax_prev = smax;
        vb_prev = t % 3;
      }

      if (t + 1 < ntile) writeV((t + 1) % 3, c0, c1);

      if (issue)
        asm volatile("s_waitcnt vmcnt(4) lgkmcnt(0)" ::: "memory");  // keep this iter's 4 in flight
      else
        asm volatile("s_waitcnt vmcnt(0) lgkmcnt(0)" ::: "memory");  // tail: full drain
      __builtin_amdgcn_s_barrier();
      __builtin_amdgcn_sched_barrier(0);
    };

    for (int t = 0; t < ntile; t += 2) {
      subiter(t, vA0, vA1, vB0, vB1);       // fill A (tile t+2), consume B (tile t+1)
      subiter(t + 1, vB0, vB1, vA0, vA1);   // fill B (tile t+3), consume A (tile t+2)
    }
    if (smax_prev >= 0) doPV();

    // ---- epilogue: merge l across lane pair, normalize, transpose, store ----
    float l_tot = l_r + __shfl_xor(l_r, 32);
    __syncthreads();   // all waves done reading K/V LDS before overlay
    uint16_t* ow = ((uint16_t*)Ks) + wid * 2048;  // per-warp [32 q][64 hd] (warp-private)
    float rl = 1.0f / l_tot;
#pragma unroll
    for (int f = 0; f < 2; ++f) {
#pragma unroll
      for (int r = 0; r < 16; r += 2) {
        int hd = 32 * f + (r & 3) + 8 * (r >> 2) + 4 * hi;
        float v0 = (f ? acc1[r] : acc0[r]) * rl;
        float v1 = (f ? acc1[r + 1] : acc0[r + 1]) * rl;
        *(uint32_t*)&ow[l31 * 64 + (hd ^ ((l31 & 7) << 3))] = cvt_pk(v0, v1);
      }
    }
    // warp-private region: no barrier needed between write and read
    int row = lane >> 1, cb = (lane & 1) * 32;
    int q = q0 + wid * 32 + row;
    int rs = (row & 7) << 3;
    uint16_t* dst = &attnb[(size_t)(b * T + q) * 1024 + hoff + cb];
#pragma unroll
    for (int cc = 0; cc < 4; ++cc)
      *(uint4*)&dst[cc * 8] = *(const uint4*)&ow[row * 64 + ((cb + cc * 8) ^ rs)];
    __syncthreads();   // epilogue reads done before next part restages Ks
  }
}

// ---------------- host ----------------
extern "C" void kernel_launch(void* const* d_in, const int* in_sizes, int n_in,
                              void* d_out, int out_size, void* d_ws, size_t ws_size,
                              hipStream_t stream) {
  const float* x = (const float*)d_in[0];
  const float* qkv_w = (const float*)d_in[1];
  const float* out_w = (const float*)d_in[2];
  const float* out_b = (const float*)d_in[3];
  float* out = (float*)d_out;

  char* ws = (char*)d_ws;
  uint16_t* xb    = (uint16_t*)(ws);
  uint16_t* qkvb  = (uint16_t*)(ws + 16777216);
  uint16_t* attnb = (uint16_t*)(ws + 67108864);
  uint16_t* wqkvb = (uint16_t*)(ws + 83886080);
  uint16_t* wob   = (uint16_t*)(ws + 90177536);

  cvt_all<<<6144, 256, 0, stream>>>(x, qkv_w, out_w, xb, wqkvb, wob);

  gemm_bt<0><<<1536, 256, 0, stream>>>(xb, wqkvb, (void*)qkvb, nullptr,
                                       8192, 3072, 1024, 24, 1536);
  flash_attn<<<768, 256, 0, stream>>>(qkvb, attnb);
  gemm_bt<1><<<512, 256, 0, stream>>>(attnb, wob, (void*)out, out_b,
                                      8192, 1024, 1024, 8, 512);
}

// Round 8
// 197.314 us; speedup vs baseline: 1.2241x; 1.0421x over previous
//
#include <hip/hip_runtime.h>
#include <stdint.h>

// Shapes (fixed): x [4,2048,1024] f32, qkv_w [3072,1024] f32, out_w [1024,1024] f32,
// out_b [1024] f32, out [4,2048,1024] f32.
// Pipeline: cvt->bf16 (fused), GEMM qkv = x@qkv_w^T, flash attn (32x32 S^T/O^T,
// in-reg softmax, cross-tile PV pipeline, counted-vmcnt barriers), GEMM out.
//
// Attention grid (round 8): 768 blocks; bh = did&63 (so did%8 == bh%8 -> all 12
// blocks of one head on ONE XCD; its 8 heads x 512KB K/V = 4MB = that XCD's L2.
// Round 7's bh=(did&255)>>2 spread heads over 4 XCDs -> FETCH 29->104MB thrash).
// k = did>>6 in 0..11 selects work; co-resident triples {k,k+4,k+8} (dispatch
// model: XCD=did%8, CU slot=(did/8)%32) each sum to EXACTLY 68 kv-tiles:
// {qb15|pair70|pair61} {qb14|qb10|pair52} {qb13|qb9|pair43} {qb12|qb11|qb8}.

typedef __bf16 bfx8 __attribute__((ext_vector_type(8)));
typedef float f32x4 __attribute__((ext_vector_type(4)));
typedef float f32x16 __attribute__((ext_vector_type(16)));

__device__ __forceinline__ uint16_t f2b(float f) {
  uint32_t u = __float_as_uint(f);
  u += 0x7fff + ((u >> 16) & 1);   // RNE
  return (uint16_t)(u >> 16);
}

__device__ __forceinline__ uint32_t cvt_pk(float lo, float hi) {
  uint32_t r;
  asm("v_cvt_pk_bf16_f32 %0, %1, %2" : "=v"(r) : "v"(lo), "v"(hi));
  return r;
}

__device__ __forceinline__ void gld16(const void* g, void* l) {
  __builtin_amdgcn_global_load_lds((const __attribute__((address_space(1))) void*)g,
                                   (__attribute__((address_space(3))) void*)l,
                                   16, 0, 0);
}

// ---------------- fused f32 -> bf16 convert (8 elems/thread, 3 tensors) -----------
__global__ __launch_bounds__(256) void cvt_all(const float* __restrict__ x,
                                               const float* __restrict__ w1,
                                               const float* __restrict__ w2,
                                               uint16_t* __restrict__ xb,
                                               uint16_t* __restrict__ w1b,
                                               uint16_t* __restrict__ w2b) {
  int i = blockIdx.x * 256 + threadIdx.x;
  const float* in;
  uint16_t* out;
  if (i < 1048576) { in = x; out = xb; }
  else if (i < 1048576 + 393216) { in = w1; out = w1b; i -= 1048576; }
  else { in = w2; out = w2b; i -= 1048576 + 393216; }
  float4 a = ((const float4*)in)[2 * i];
  float4 b = ((const float4*)in)[2 * i + 1];
  union { uint16_t u[8]; uint4 v; } pk;
  pk.u[0] = f2b(a.x); pk.u[1] = f2b(a.y); pk.u[2] = f2b(a.z); pk.u[3] = f2b(a.w);
  pk.u[4] = f2b(b.x); pk.u[5] = f2b(b.y); pk.u[6] = f2b(b.z); pk.u[7] = f2b(b.w);
  ((uint4*)out)[i] = pk.v;
}

// ---------------- GEMM: C[M,N] = A[M,K] * B[N,K]^T (+bias) ----------------
template <int OUTF32>
__global__ __launch_bounds__(256) void gemm_bt(const uint16_t* __restrict__ A,
                                               const uint16_t* __restrict__ B,
                                               void* __restrict__ Cout,
                                               const float* __restrict__ bias,
                                               int M, int N, int K, int nbx, int nwg) {
  __shared__ alignas(16) uint16_t As[2][128 * 32];
  __shared__ alignas(16) uint16_t Bs[2][128 * 32];

  int did = blockIdx.x;
  int wg = (did & 7) * (nwg >> 3) + (did >> 3);
  int bx = wg % nbx, by = wg / nbx;
  int m0 = by * 128, n0 = bx * 128;

  int tid = threadIdx.x;
  int lane = tid & 63, wid = tid >> 6;
  int wm = wid >> 1, wn = wid & 1;

  int rs = wid * 16 + (lane >> 2);
  int cs = (lane & 3) * 8;

  f32x4 acc[4][4] = {};

  auto stage = [&](int buf, int kt) {
    int k0 = kt * 32;
    gld16(&A[(size_t)(m0 + rs) * K + k0 + cs],      &As[buf][wid * 512]);
    gld16(&A[(size_t)(m0 + rs + 64) * K + k0 + cs], &As[buf][wid * 512 + 2048]);
    gld16(&B[(size_t)(n0 + rs) * K + k0 + cs],      &Bs[buf][wid * 512]);
    gld16(&B[(size_t)(n0 + rs + 64) * K + k0 + cs], &Bs[buf][wid * 512 + 2048]);
  };

  stage(0, 0);
  __syncthreads();

  int nk = K >> 5;
  int cur = 0;
  int ko = (lane >> 4) * 8;
  for (int kt = 0; kt < nk; ++kt) {
    if (kt + 1 < nk) stage(cur ^ 1, kt + 1);
    bfx8 a[4], b[4];
#pragma unroll
    for (int mi = 0; mi < 4; ++mi)
      a[mi] = *(const bfx8*)&As[cur][(wm * 64 + mi * 16 + (lane & 15)) * 32 + ko];
#pragma unroll
    for (int ni = 0; ni < 4; ++ni)
      b[ni] = *(const bfx8*)&Bs[cur][(wn * 64 + ni * 16 + (lane & 15)) * 32 + ko];
#pragma unroll
    for (int mi = 0; mi < 4; ++mi)
#pragma unroll
      for (int ni = 0; ni < 4; ++ni)
        acc[mi][ni] =
            __builtin_amdgcn_mfma_f32_16x16x32_bf16(a[mi], b[ni], acc[mi][ni], 0, 0, 0);
    __syncthreads();
    cur ^= 1;
  }

#pragma unroll
  for (int mi = 0; mi < 4; ++mi) {
    int row = m0 + wm * 64 + mi * 16 + ((lane >> 4) << 2);
#pragma unroll
    for (int ni = 0; ni < 4; ++ni) {
      int col = n0 + wn * 64 + ni * 16 + (lane & 15);
#pragma unroll
      for (int r = 0; r < 4; ++r) {
        float v = acc[mi][ni][r];
        if (OUTF32)
          ((float*)Cout)[(size_t)(row + r) * N + col] = v + bias[col];
        else
          ((uint16_t*)Cout)[(size_t)(row + r) * N + col] = f2b(v);
      }
    }
  }
}

// ---------------- flash attention (causal), pipelined 32x32 S^T / O^T ----------
// See header comment for the 768-block partition. 4 waves x 32 q. Distance-2
// prefetch; K triple-buffered LDS (global_load_lds), V triple-buffered LDS via
// 2-bank register staging. Raw s_barrier with COUNTED vmcnt(4). launch_bounds
// (256,2): (256,3) forced VGPR 124->84 and spilled (round-6: 73MB scratch).
__global__ __launch_bounds__(256, 2) void flash_attn(const uint16_t* __restrict__ qkv,
                                                     uint16_t* __restrict__ attnb) {
  const int T = 2048, D3 = 3072;
  const float CSC = 0.125f * 1.44269504f;  // scale * log2(e)
  __shared__ alignas(16) uint16_t Ks[3][64 * 64];
  __shared__ alignas(16) uint16_t Vt[3][64 * 64];   // V^T: [hd][kv]

  int did = blockIdx.x;
  int bh = did & 63;             // did%8 == bh%8 -> one XCD per head group
  int k = did >> 6;              // 0..11: work selector
  int b = bh >> 4, h = bh & 15;

  // triples {k,k+4,k+8} each sum to 68 tiles
  const int P1[12] = {15, 14, 13, 12,  7, 10,  9, 11,  6,  5,  4,  8};
  const int P2[12] = {-1, -1, -1, -1,  0, -1, -1, -1,  1,  2,  3, -1};
  int p1 = P1[k], p2 = P2[k];

  int tid = threadIdx.x, lane = tid & 63, wid = tid >> 6;
  int l31 = lane & 31, hi = lane >> 5;
  int swz = (lane & 7) << 3;

  size_t base = (size_t)b * T * D3;
  int hoff = h * 64;
  const uint16_t* kbase = &qkv[base + 1024 + hoff];
  const uint16_t* vbase = &qkv[base + 2048 + hoff];

  int krow = wid * 16 + (lane >> 3);
  int kc = ((lane & 7) << 3) ^ ((krow & 7) << 3);
  int vr = (tid & 31) * 2;
  int vc = (tid >> 5) * 8;

  int nparts = (p2 >= 0) ? 2 : 1;
  for (int p = 0; p < nparts; ++p) {
    int qb = (p == 0) ? p1 : p2;
    int q0 = qb << 7;
    int qw = q0 + wid * 32;
    int ntile = 2 * qb + 2;             // even

    float mC = -1e30f, l_r = 0.f;       // l_r: per-lane partial
    f32x16 acc0 = {}, acc1 = {};
    bfx8 pf[4];
    int smax_prev = -1, vb_prev = 0;

    // Q frags (B-operand): col=q=l31, k = hd = 16*h4 + 8*hi + j
    bfx8 qf[4];
    {
      const uint16_t* qp = &qkv[base + (size_t)(qw + l31) * D3 + hoff + 8 * hi];
#pragma unroll
      for (int h4 = 0; h4 < 4; ++h4) qf[h4] = *(const bfx8*)(qp + 16 * h4);
    }

    uint4 vA0, vA1, vB0, vB1;   // two V register banks (tile parity)

    auto loadV = [&](int kv0, uint4& r0, uint4& r1) {
      r0 = *(const uint4*)&vbase[(size_t)(kv0 + vr) * D3 + vc];
      r1 = *(const uint4*)&vbase[(size_t)(kv0 + vr + 1) * D3 + vc];
    };
    auto stageK = [&](int buf, int kv0) {
      gld16(&kbase[(size_t)(kv0 + krow) * D3 + kc], &Ks[buf][wid * 1024]);
      gld16(&kbase[(size_t)(kv0 + krow + 8) * D3 + kc], &Ks[buf][wid * 1024 + 512]);
    };
    auto writeV = [&](int vb, const uint4& r0, const uint4& r1) {
      union { uint4 v; uint16_t u[8]; } x, y;
      x.v = r0; y.v = r1;
#pragma unroll
      for (int jj = 0; jj < 8; ++jj) {
        int hd = vc + jj;
        uint32_t pk = (uint32_t)x.u[jj] | ((uint32_t)y.u[jj] << 16);
        *(uint32_t*)&Vt[vb][hd * 64 + (vr ^ ((hd & 7) << 3))] = pk;
      }
    };
    auto doPV = [&]() {
      const uint16_t* vp = &Vt[vb_prev][0];
      __builtin_amdgcn_s_setprio(1);
#pragma unroll
      for (int s = 0; s < 4; ++s) {
        if (s <= smax_prev) {
          bfx8 v0 = *(const bfx8*)&vp[l31 * 64 + ((16 * s + 8 * hi) ^ swz)];
          acc0 = __builtin_amdgcn_mfma_f32_32x32x16_bf16(v0, pf[s], acc0, 0, 0, 0);
          bfx8 v1 = *(const bfx8*)&vp[(32 + l31) * 64 + ((16 * s + 8 * hi) ^ swz)];
          acc1 = __builtin_amdgcn_mfma_f32_32x32x16_bf16(v1, pf[s], acc1, 0, 0, 0);
        }
      }
      __builtin_amdgcn_s_setprio(0);
    };

    // ---- prologue: stage tiles 0,1 fully; full drain once ----
    loadV(0, vA0, vA1);
    stageK(0, 0);
    writeV(0, vA0, vA1);          // compiler inserts the vmcnt wait for vA regs
    loadV(64, vB0, vB1);          // tile 1 -> bank B (written at iter 0)
    stageK(1, 64);
    asm volatile("s_waitcnt vmcnt(0) lgkmcnt(0)" ::: "memory");
    __builtin_amdgcn_s_barrier();
    __builtin_amdgcn_sched_barrier(0);

    auto subiter = [&](int t, uint4& f0, uint4& f1, uint4& c0, uint4& c1) {
      int kv0 = t << 6;
      bool issue = (t + 2 < ntile);
      if (issue) {
        loadV((t + 2) << 6, f0, f1);
        stageK((t + 2) % 3, (t + 2) << 6);
      }
      bool active = (kv0 <= qw);
      int tmax = (qw > kv0) ? 2 : 1;
      f32x16 st0 = {}, st1 = {};
      if (active) {
        // ---- S^T = K * Q^T ----
        const uint16_t* kp = &Ks[t % 3][0];
        __builtin_amdgcn_s_setprio(1);
#pragma unroll
        for (int h4 = 0; h4 < 4; ++h4) {
          bfx8 kf0 = *(const bfx8*)&kp[l31 * 64 + ((16 * h4 + 8 * hi) ^ swz)];
          st0 = __builtin_amdgcn_mfma_f32_32x32x16_bf16(kf0, qf[h4], st0, 0, 0, 0);
          if (tmax == 2) {
            bfx8 kf1 = *(const bfx8*)&kp[(32 + l31) * 64 + ((16 * h4 + 8 * hi) ^ swz)];
            st1 = __builtin_amdgcn_mfma_f32_32x32x16_bf16(kf1, qf[h4], st1, 0, 0, 0);
          }
        }
        __builtin_amdgcn_s_setprio(0);
      }

      // ---- PV of PREVIOUS tile (before any rescale of acc) ----
      if (smax_prev >= 0) { doPV(); smax_prev = -1; }

      if (active) {
        // ---- softmax (lane-local rows; st becomes P in place) ----
        int q = qw + l31;
        float mx0 = -1e30f, mx1 = -1e30f;
        if (kv0 == qw) {
#pragma unroll
          for (int r = 0; r < 16; ++r) {
            int kv = kv0 + (r & 3) + 8 * (r >> 2) + 4 * hi;
            float v = st0[r];
            if (kv > q) v = -1e30f;
            st0[r] = v;
            mx0 = fmaxf(mx0, v);
          }
        } else {
#pragma unroll
          for (int r = 0; r < 16; ++r) mx0 = fmaxf(mx0, st0[r]);
        }
        if (tmax == 2) {
          if (kv0 + 32 == qw) {
#pragma unroll
            for (int r = 0; r < 16; ++r) {
              int kv = kv0 + 32 + (r & 3) + 8 * (r >> 2) + 4 * hi;
              float v = st1[r];
              if (kv > q) v = -1e30f;
              st1[r] = v;
              mx1 = fmaxf(mx1, v);
            }
          } else {
#pragma unroll
            for (int r = 0; r < 16; ++r) mx1 = fmaxf(mx1, st1[r]);
          }
        }
        float mS = fmaxf(mx0, mx1) * CSC;
        if (!__all(mS - mC <= 8.0f)) {   // defer-max: rare path has the only shuffle
          float mSp = fmaxf(mS, __shfl_xor(mS, 32));
          float mCn = fmaxf(mC, mSp);
          float fac = __builtin_amdgcn_exp2f(mC - mCn);
          mC = mCn;
          l_r *= fac;
          acc0 *= fac;
          acc1 *= fac;
        }
        float l0 = 0.f, l1 = 0.f, l2 = 0.f, l3 = 0.f;
#pragma unroll
        for (int r = 0; r < 16; r += 4) {
          float e0 = __builtin_amdgcn_exp2f(fmaf(st0[r], CSC, -mC));
          float e1 = __builtin_amdgcn_exp2f(fmaf(st0[r + 1], CSC, -mC));
          float e2 = __builtin_amdgcn_exp2f(fmaf(st0[r + 2], CSC, -mC));
          float e3 = __builtin_amdgcn_exp2f(fmaf(st0[r + 3], CSC, -mC));
          st0[r] = e0; st0[r + 1] = e1; st0[r + 2] = e2; st0[r + 3] = e3;
          l0 += e0; l1 += e1; l2 += e2; l3 += e3;
        }
        if (tmax == 2) {
#pragma unroll
          for (int r = 0; r < 16; r += 4) {
            float e0 = __builtin_amdgcn_exp2f(fmaf(st1[r], CSC, -mC));
            float e1 = __builtin_amdgcn_exp2f(fmaf(st1[r + 1], CSC, -mC));
            float e2 = __builtin_amdgcn_exp2f(fmaf(st1[r + 2], CSC, -mC));
            float e3 = __builtin_amdgcn_exp2f(fmaf(st1[r + 3], CSC, -mC));
            st1[r] = e0; st1[r + 1] = e1; st1[r + 2] = e2; st1[r + 3] = e3;
            l0 += e0; l1 += e1; l2 += e2; l3 += e3;
          }
        }
        l_r += (l0 + l1) + (l2 + l3);

        // ---- pack P -> bf16 B-frags in registers ----
        int smax = (qw + 31 - kv0) >> 4;
        if (smax > 3) smax = 3;
#pragma unroll
        for (int s = 0; s < 4; ++s) {
          if (s <= smax) {
            int pb = 8 * (s & 1);
            uint32_t W0, W1, W2, W3;
            if (s < 2) {
              W0 = cvt_pk(st0[pb + 0], st0[pb + 1]);
              W1 = cvt_pk(st0[pb + 2], st0[pb + 3]);
              W2 = cvt_pk(st0[pb + 4], st0[pb + 5]);
              W3 = cvt_pk(st0[pb + 6], st0[pb + 7]);
            } else {
              W0 = cvt_pk(st1[pb + 0], st1[pb + 1]);
              W1 = cvt_pk(st1[pb + 2], st1[pb + 3]);
              W2 = cvt_pk(st1[pb + 4], st1[pb + 5]);
              W3 = cvt_pk(st1[pb + 6], st1[pb + 7]);
            }
            auto rA = __builtin_amdgcn_permlane32_swap(W0, W2, false, false);
            auto rB = __builtin_amdgcn_permlane32_swap(W1, W3, false, false);
            union { uint32_t u[4]; bfx8 v; } pk;
            pk.u[0] = rA[0]; pk.u[1] = rB[0]; pk.u[2] = rA[1]; pk.u[3] = rB[1];
            pf[s] = pk.v;
          }
        }
        smax_prev = smax;
        vb_prev = t % 3;
      }

      if (t + 1 < ntile) writeV((t + 1) % 3, c0, c1);

      if (issue)
        asm volatile("s_waitcnt vmcnt(4) lgkmcnt(0)" ::: "memory");  // keep this iter's 4 in flight
      else
        asm volatile("s_waitcnt vmcnt(0) lgkmcnt(0)" ::: "memory");  // tail: full drain
      __builtin_amdgcn_s_barrier();
      __builtin_amdgcn_sched_barrier(0);
    };

    for (int t = 0; t < ntile; t += 2) {
      subiter(t, vA0, vA1, vB0, vB1);       // fill A (tile t+2), consume B (tile t+1)
      subiter(t + 1, vB0, vB1, vA0, vA1);   // fill B (tile t+3), consume A (tile t+2)
    }
    if (smax_prev >= 0) doPV();

    // ---- epilogue: merge l across lane pair, normalize, transpose, store ----
    float l_tot = l_r + __shfl_xor(l_r, 32);
    __syncthreads();   // all waves done reading K/V LDS before overlay
    uint16_t* ow = ((uint16_t*)Ks) + wid * 2048;  // per-warp [32 q][64 hd] (warp-private)
    float rl = 1.0f / l_tot;
#pragma unroll
    for (int f = 0; f < 2; ++f) {
#pragma unroll
      for (int r = 0; r < 16; r += 2) {
        int hd = 32 * f + (r & 3) + 8 * (r >> 2) + 4 * hi;
        float v0 = (f ? acc1[r] : acc0[r]) * rl;
        float v1 = (f ? acc1[r + 1] : acc0[r + 1]) * rl;
        *(uint32_t*)&ow[l31 * 64 + (hd ^ ((l31 & 7) << 3))] = cvt_pk(v0, v1);
      }
    }
    // warp-private region: no barrier needed between write and read
    int row = lane >> 1, cb = (lane & 1) * 32;
    int q = q0 + wid * 32 + row;
    int rs = (row & 7) << 3;
    uint16_t* dst = &attnb[(size_t)(b * T + q) * 1024 + hoff + cb];
#pragma unroll
    for (int cc = 0; cc < 4; ++cc)
      *(uint4*)&dst[cc * 8] = *(const uint4*)&ow[row * 64 + ((cb + cc * 8) ^ rs)];
    __syncthreads();   // epilogue reads done before next part restages Ks
  }
}

// ---------------- host ----------------
extern "C" void kernel_launch(void* const* d_in, const int* in_sizes, int n_in,
                              void* d_out, int out_size, void* d_ws, size_t ws_size,
                              hipStream_t stream) {
  const float* x = (const float*)d_in[0];
  const float* qkv_w = (const float*)d_in[1];
  const float* out_w = (const float*)d_in[2];
  const float* out_b = (const float*)d_in[3];
  float* out = (float*)d_out;

  char* ws = (char*)d_ws;
  uint16_t* xb    = (uint16_t*)(ws);
  uint16_t* qkvb  = (uint16_t*)(ws + 16777216);
  uint16_t* attnb = (uint16_t*)(ws + 67108864);
  uint16_t* wqkvb = (uint16_t*)(ws + 83886080);
  uint16_t* wob   = (uint16_t*)(ws + 90177536);

  cvt_all<<<6144, 256, 0, stream>>>(x, qkv_w, out_w, xb, wqkvb, wob);

  gemm_bt<0><<<1536, 256, 0, stream>>>(xb, wqkvb, (void*)qkvb, nullptr,
                                       8192, 3072, 1024, 24, 1536);
  flash_attn<<<768, 256, 0, stream>>>(qkvb, attnb);
  gemm_bt<1><<<512, 256, 0, stream>>>(attnb, wob, (void*)out, out_b,
                                      8192, 1024, 1024, 8, 512);
}